// Round 2
// baseline (147.064 us; speedup 1.0000x reference)
//
#include <hip/hip_runtime.h>
#include <stdint.h>
#include <math.h>

#define TPB   512    // 8 waves/block -> 4 blocks/CU hits the 32-wave cap
#define KTOP  100
#define K1    128    // selection rank cut (per-slice in s1, per-image in s2)
#define KSLOT 192    // per-slice emitted u32 slots (>= K1 + tie-bin margin)
#define CAP   768    // stage-1 survivor capacity (expected ~450/slice, +13 sigma)
#define SR    8      // slice rows

#define HB 272
#define WB 480
#define NSB 34       // 272/8
#define HP 68
#define WP 120
#define NSP 9        // ceil(68/8), last slice 4 rows
#define NB 64

// ============================================================================
// Validated invariants (rounds 2-5, absmax 0.0):
//  - np-f32 softmax p is a MONOTONE function G of D = fl32(x1-x0);
//    G collapse window |dD| < ~6e-8*e^|D| (< 0.25 for |D| < 13).
//  - NMS: keep iff p >= all 8 neighbors; D-space fast path + exact G on ties.
//  - top-k tie order: (p desc, idx asc)  ==  u64 key (p_bits<<32 | ~idx) desc.
//  - 16-bit D-key rank-128 cut contains the exact top-100 set.
// R7: R6's deferred-tie queue REVERTED (cost +3.6us: stage1 is stall-bound,
//     not VALU-bound; the queue added serialization). New: wave-aggregated
//     LDS atomics (ballot leader) for counters and clustered per-bin
//     histogram adds (keys cluster in ~5 exponent bins -> hot-bin lane
//     serialization); stage2 bitonic sort (36 barriers) replaced by
//     rank-by-counting over unique u64 keys (2 barriers); stage1 tile load
//     manually unrolled for 6 outstanding float4 loads.
// ============================================================================
__device__ __forceinline__ float G_exact(float D) {
    float t = -fabsf(D);
    float etf = (float)exp((double)t);       // correctly-rounded f32 exp
    return (D > 0.0f) ? __fdiv_rn(1.0f, __fadd_rn(etf, 1.0f))
                      : __fdiv_rn(etf, __fadd_rn(1.0f, etf));
}

__device__ __forceinline__ uint32_t flip_f32(float D) {
    uint32_t u = __float_as_uint(D);
    return (u & 0x80000000u) ? ~u : (u | 0x80000000u);
}

// Wave-aggregated counter push: one atomicAdd per wave, each active lane gets
// its slot = base + (# active lanes below it). Uniform call site required
// (exec-masked lanes simply don't participate in the ballot).
__device__ __forceinline__ int agg_push(int* ctr, bool active) {
    uint64_t m = __ballot(active);
    int pos = -1;
    if (active) {
        int lane = threadIdx.x & 63;
        int lead = __ffsll((unsigned long long)m) - 1;
        int before = (int)__popcll(m & ((1ull << lane) - 1ull));
        int base = 0;
        if (lane == lead) base = atomicAdd(ctr, (int)__popcll(m));
        base = __shfl(base, lead, 64);
        pos = base + before;
    }
    return pos;
}

// Clustered histogram add: one atomicAdd per DISTINCT bin per wave (keys
// cluster into ~5 exponent bins -> replaces up to 64-way same-address
// serialization with a ~5-iteration leader loop).
__device__ __forceinline__ void hist_clustered(uint32_t* hist, uint32_t bin, bool active) {
    uint64_t todo = __ballot(active);
    while (todo) {
        int lead = __ffsll((unsigned long long)todo) - 1;
        uint32_t b = (uint32_t)__shfl((int)bin, lead, 64);
        uint64_t same = __ballot(active && (bin == b));
        if ((int)(threadIdx.x & 63) == lead) atomicAdd(&hist[b], (uint32_t)__popcll(same));
        todo &= ~same;
    }
}

// In-place suffix-sum of 256 u32 bins: hist[i] <- sum_{j>=i} hist[j].
// Wave 0 via shuffles; ends with a barrier. (validated round 4)
__device__ __forceinline__ void suffix_scan_256(uint32_t* hist) {
    if (threadIdx.x < 64) {
        int lane = threadIdx.x;
        uint32_t h0 = hist[4*lane+0], h1 = hist[4*lane+1];
        uint32_t h2 = hist[4*lane+2], h3 = hist[4*lane+3];
        uint32_t tot = h0 + h1 + h2 + h3;
        uint32_t run = tot;
        #pragma unroll
        for (int d = 1; d < 64; d <<= 1) {
            uint32_t o = __shfl_down(run, d, 64);
            if (lane + d < 64) run += o;
        }
        uint32_t ab = run - tot;
        hist[4*lane+3] = ab + h3;
        hist[4*lane+2] = ab + h3 + h2;
        hist[4*lane+1] = ab + h3 + h2 + h1;
        hist[4*lane+0] = ab + tot;
    }
    __syncthreads();
}

// 6-wide row window [c4-1 .. c4+4] from the LDS D-tile (OOB -> -inf).
template<int W>
__device__ __forceinline__ void row6(const float* df, int row, int c4, float* a) {
    const float4 m = ((const float4*)df)[(row * W + c4) >> 2];
    a[1] = m.x; a[2] = m.y; a[3] = m.z; a[4] = m.w;
    a[0] = (c4 > 0)     ? df[row * W + c4 - 1] : -INFINITY;
    a[5] = (c4 + 4 < W) ? df[row * W + c4 + 4] : -INFINITY;
}

// ---- stage 1 body: NMS + D16 radix-select, emit u32 slots ------------------
// Templated W/H/NS -> all divisions become compile-time magic-mul/shift.
template<int H, int W, int NS>
__device__ __forceinline__ void stage1_impl(const float* __restrict__ x,
                                            int s, int b,
                                            uint32_t* __restrict__ key_out,
                                            unsigned char* smem)
{
    constexpr int W4 = W / 4;
    constexpr int tileRows = SR + 2;
    const int r0 = s * SR;
    const int rows = (H - r0 < SR) ? (H - r0) : SR;

    float*    df   = (float*)smem;                         // tileRows * W
    uint32_t* surv = (uint32_t*)(df + tileRows * W);       // CAP
    uint32_t* hist = surv + CAP;                           // 256
    uint32_t* outb = hist + 256;                           // KSLOT
    __shared__ int s_cnt, s_out;
    __shared__ uint32_t s_bin, s_ab, s_bin2, s_none;
    if (threadIdx.x == 0) { s_cnt = 0; s_out = 0; s_none = 0; }
    if (threadIdx.x < 256) hist[threadIdx.x] = 0;

    const float*  x0  = x + (size_t)b * 2 * H * W;
    const float*  x1  = x0 + (size_t)H * W;
    const float4* x0v = (const float4*)x0;
    const float4* x1v = (const float4*)x1;
    float4* dfv = (float4*)df;

    // D tile (rows r0-1 .. r0+SR), float4-vectorized; OOB rows -> -inf.
    // Manually chunk-unrolled: all global loads issued before any use
    // (6 outstanding float4 loads for the ball tile).
    constexpr int nt4 = tileRows * W4;
    constexpr int NCH = (nt4 + TPB - 1) / TPB;
    {
        float4 ra[NCH], rc[NCH];
        #pragma unroll
        for (int u = 0; u < NCH; ++u) {
            int t = threadIdx.x + u * TPB;
            if (t < nt4) {
                int tr = t / W4, c4 = t - tr * W4;        // compile-time divisor
                int r = r0 - 1 + tr;
                if (r >= 0 && r < H) {
                    ra[u] = x0v[r * W4 + c4];
                    rc[u] = x1v[r * W4 + c4];
                } else {
                    ra[u] = make_float4(0.f, 0.f, 0.f, 0.f);
                    rc[u] = make_float4(-INFINITY, -INFINITY, -INFINITY, -INFINITY);
                }
            }
        }
        #pragma unroll
        for (int u = 0; u < NCH; ++u) {
            int t = threadIdx.x + u * TPB;
            if (t < nt4) {
                float4 a = ra[u], c = rc[u];
                float4 d4;
                d4.x = __fsub_rn(c.x, a.x);
                d4.y = __fsub_rn(c.y, a.y);
                d4.z = __fsub_rn(c.z, a.z);
                d4.w = __fsub_rn(c.w, a.w);
                dfv[t] = d4;
            }
        }
    }
    __syncthreads();

    // NMS (4 cells/iter) + level-1 histogram fused into the keep path.
    // Keep-decision identical to the validated round-0 form (inline exact-G
    // tie resolution); emission uses wave-aggregated atomics.
    const int groups = rows * W4;
    for (int g = threadIdx.x; g < groups; g += TPB) {
        int lr = g / W4, c4 = (g - lr * W4) << 2; // compile-time divisor
        int tr = lr + 1;
        float ap[6], ac[6], an[6];
        row6<W>(df, tr - 1, c4, ap);
        row6<W>(df, tr,     c4, ac);
        row6<W>(df, tr + 1, c4, an);
        #pragma unroll
        for (int j = 0; j < 4; ++j) {
            float v = ac[j + 1];
            float mx = fmaxf(fmaxf(fmaxf(ap[j], ap[j+1]), fmaxf(ap[j+2], an[j])),
                             fmaxf(fmaxf(an[j+1], an[j+2]), fmaxf(ac[j], ac[j+2])));
            bool keep;
            if (v >= mx) keep = true;                              // exact
            else if (mx - v >= 0.25f && mx < 13.0f) keep = false;  // G distinct
            else keep = (G_exact(v) == G_exact(mx));               // rare tie
            uint32_t key16 = flip_f32(v) >> 16;
            int pos = agg_push(&s_cnt, keep);
            if (keep && pos < CAP)
                surv[pos] = (key16 << 16) | ((uint32_t)lr << 9) | (uint32_t)(c4 + j);
            hist_clustered(hist, key16 >> 8, keep);
        }
    }
    __syncthreads();
    const int n = (s_cnt < CAP) ? s_cnt : CAP;

    // Level-1 select on D16 high byte.
    suffix_scan_256(hist);
    if (threadIdx.x < 256) {
        uint32_t si = hist[threadIdx.x];
        uint32_t sn = (threadIdx.x < 255) ? hist[threadIdx.x + 1] : 0u;
        if (threadIdx.x == 0 && si < K1) s_none = 1;
        if (si >= K1 && sn < K1) { s_bin = threadIdx.x; s_ab = sn; }
    }
    __syncthreads();

    uint32_t T16 = 0;
    if (!s_none) {
        const uint32_t b3 = s_bin;
        const uint32_t k2 = K1 - s_ab;
        if (threadIdx.x < 256) hist[threadIdx.x] = 0;
        __syncthreads();
        for (int t = threadIdx.x; t < n; t += TPB) {
            uint32_t sv = surv[t];
            if ((sv >> 24) == b3) atomicAdd(&hist[(sv >> 16) & 255u], 1u);
        }
        __syncthreads();
        suffix_scan_256(hist);
        if (threadIdx.x < 256) {
            uint32_t si = hist[threadIdx.x];
            uint32_t sn = (threadIdx.x < 255) ? hist[threadIdx.x + 1] : 0u;
            if (si >= k2 && sn < k2) s_bin2 = threadIdx.x;
        }
        __syncthreads();
        T16 = (b3 << 8) | s_bin2;
    }

    // Compact survivors with D16 >= T16 (unsorted), zero-padded to KSLOT.
    if (threadIdx.x < KSLOT) outb[threadIdx.x] = 0;
    __syncthreads();
    for (int t = threadIdx.x; t < n; t += TPB) {
        uint32_t sv = surv[t];
        bool take = ((sv >> 16) >= T16);
        int pos = agg_push(&s_out, take);
        if (take && pos < KSLOT) outb[pos] = sv;
    }
    __syncthreads();
    if (threadIdx.x < KSLOT)
        key_out[((size_t)b * NS + s) * KSLOT + threadIdx.x] = outb[threadIdx.x];
}

__global__ __launch_bounds__(TPB) void stage1(const float* __restrict__ bmap,
                                              const float* __restrict__ pmap,
                                              uint32_t* __restrict__ bkey,
                                              uint32_t* __restrict__ pkey)
{
    extern __shared__ unsigned char smem[];
    if (blockIdx.x < NSB)
        stage1_impl<HB, WB, NSB>(bmap, blockIdx.x, blockIdx.y, bkey, smem);
    else
        stage1_impl<HP, WP, NSP>(pmap, blockIdx.x - NSB, blockIdx.y, pkey, smem);
}

// ---- stage 2 body: D16 select -> exact-p re-rank of <=256 -> decode --------
template<int H, int W, int NS, bool BALL>
__device__ __forceinline__ void stage2_impl(const float* __restrict__ xmap,
                                            const float* __restrict__ pbbox,
                                            const uint32_t* __restrict__ key_in,
                                            float* __restrict__ outp,
                                            int b, unsigned char* smem)
{
    constexpr int M = NS * KSLOT;
    const float* x0 = xmap + (size_t)b * 2 * H * W;
    const float* x1 = x0 + (size_t)H * W;
    const uint32_t* kin = key_in + (size_t)b * M;

    uint32_t* keys = (uint32_t*)smem;           // M
    uint32_t* hist = keys + M;                  // 256 (reused as rank array)
    uint64_t* outb = (uint64_t*)(hist + 256);   // 256
    __shared__ int s_out;
    __shared__ uint32_t s_bin, s_ab, s_bin2, s_none;
    if (threadIdx.x == 0) { s_out = 0; s_none = 0; }
    if (threadIdx.x < 256) hist[threadIdx.x] = 0;

    // Defensive zero of the 100 output rows (always overwritten in practice;
    // ordered before the rank-scatter by the intervening barriers).
    for (int t = threadIdx.x; t < KTOP * 5; t += TPB) outp[t] = 0.f;
    __syncthreads();

    // Load keys + level-1 histogram in one pass (clustered bin atomics).
    for (int t = threadIdx.x; t < M; t += TPB) {
        uint32_t k = kin[t];
        keys[t] = k;
        hist_clustered(hist, k >> 24, k != 0);
    }
    __syncthreads();
    suffix_scan_256(hist);
    if (threadIdx.x < 256) {
        uint32_t si = hist[threadIdx.x];
        uint32_t sn = (threadIdx.x < 255) ? hist[threadIdx.x + 1] : 0u;
        if (threadIdx.x == 0 && si < K1) s_none = 1;
        if (si >= K1 && sn < K1) { s_bin = threadIdx.x; s_ab = sn; }
    }
    __syncthreads();

    uint32_t T16 = 0;
    if (!s_none) {
        const uint32_t b3 = s_bin;
        const uint32_t k2 = K1 - s_ab;
        if (threadIdx.x < 256) hist[threadIdx.x] = 0;
        __syncthreads();
        for (int t = threadIdx.x; t < M; t += TPB) {
            uint32_t k = keys[t];
            if (k && (k >> 24) == b3) atomicAdd(&hist[(k >> 16) & 255u], 1u);
        }
        __syncthreads();
        suffix_scan_256(hist);
        if (threadIdx.x < 256) {
            uint32_t si = hist[threadIdx.x];
            uint32_t sn = (threadIdx.x < 255) ? hist[threadIdx.x + 1] : 0u;
            if (si >= k2 && sn < k2) s_bin2 = threadIdx.x;
        }
        __syncthreads();
        T16 = (b3 << 8) | s_bin2;
    }

    // Compact finalists; compute exact np p only here (D re-read from map).
    if (threadIdx.x < 256) { outb[threadIdx.x] = 0; hist[threadIdx.x] = 0; }
    __syncthreads();
    for (int t = threadIdx.x; t < M; t += TPB) {
        uint32_t k = keys[t];
        bool take = (k != 0) && ((k >> 16) >= T16);
        int pos = agg_push(&s_out, take);
        if (take && pos < 256) {
            int sIdx = t / KSLOT;                      // compile-time divisor
            int lr = (k >> 9) & 7, c = k & 511;
            int gidx = (sIdx * SR + lr) * W + c;
            float D = __fsub_rn(x1[gidx], x0[gidx]);
            float p = G_exact(D);
            outb[pos] = ((uint64_t)__float_as_uint(p) << 32) | (uint32_t)(~gidx);
        }
    }
    __syncthreads();

    // Rank-by-counting over unique u64 keys (replaces 36-barrier bitonic).
    // Thread (i = tid&255, half = tid>>8) counts keys greater than outb[i]
    // over half the array; j is wave-uniform -> LDS broadcast reads.
    {
        int i = threadIdx.x & 255;
        int half = threadIdx.x >> 8;
        uint64_t ki = outb[i];
        uint32_t cnt = 0;
        int j0 = half * 128;
        #pragma unroll 4
        for (int j = j0; j < j0 + 128; ++j) cnt += (outb[j] > ki) ? 1u : 0u;
        atomicAdd(&hist[i], cnt);
    }
    __syncthreads();

    // Decode: finalist with rank r < KTOP writes output row r directly.
    if (threadIdx.x < 256) {
        uint64_t k = outb[threadIdx.x];
        uint32_t r = hist[threadIdx.x];
        if (k != 0 && r < KTOP) {
            int id = (int)(~(uint32_t)k);
            float val = __uint_as_float((uint32_t)(k >> 32));
            int yy = id / W, xx = id - yy * W;             // compile-time divisor
            constexpr float ds = BALL ? 4.0f : 16.0f;
            float xc = (float)xx * ds + (ds - 1.0f) * 0.5f;
            float yc = (float)yy * ds + (ds - 1.0f) * 0.5f;
            float t0 = 0.f, t1 = 0.f;
            float t2 = BALL ? 40.0f : 0.0f, t3 = BALL ? 40.0f : 0.0f;
            if (!BALL) {
                const float* bb = pbbox + (size_t)b * 4 * H * W;
                constexpr float sx = (float)W * ds, sy = (float)H * ds;
                t0 = bb[id]             * sx;
                t1 = bb[id + H * W]     * sy;
                t2 = bb[id + 2 * H * W] * sx;
                t3 = bb[id + 3 * H * W] * sy;
            }
            float bx = xc + t0, by = yc + t1;
            float* op = outp + (size_t)r * 5;
            op[0] = bx - 0.5f * t2;
            op[1] = by - 0.5f * t3;
            op[2] = bx + 0.5f * t2;
            op[3] = by + 0.5f * t3;
            op[4] = val;
        }
    }
}

__global__ __launch_bounds__(TPB) void stage2(const float* __restrict__ bmap,
                                              const float* __restrict__ pmap,
                                              const float* __restrict__ pbbox,
                                              const uint32_t* __restrict__ bkey,
                                              const uint32_t* __restrict__ pkey,
                                              float* __restrict__ out)
{
    extern __shared__ unsigned char smem[];
    if (blockIdx.x < NB) {
        int b = blockIdx.x;
        stage2_impl<HB, WB, NSB, true>(bmap, nullptr, bkey,
            out + (size_t)NB * KTOP * 5 + (size_t)b * KTOP * 5, b, smem);
    } else {
        int b = blockIdx.x - NB;
        stage2_impl<HP, WP, NSP, false>(pmap, pbbox, pkey,
            out + (size_t)b * KTOP * 5, b, smem);
    }
}

// ---- launch -----------------------------------------------------------------
extern "C" void kernel_launch(void* const* d_in, const int* in_sizes, int n_in,
                              void* d_out, int out_size, void* d_ws, size_t ws_size,
                              hipStream_t stream) {
    const float* pmap  = (const float*)d_in[0];   // [64,2,68,120]
    const float* pbbox = (const float*)d_in[1];   // [64,4,68,120]
    const float* bmap  = (const float*)d_in[2];   // [64,2,272,480]
    float* out = (float*)d_out;                   // player [64,100,5] then ball

    uint32_t* ws_bkey = (uint32_t*)d_ws;                       // 64*34*192 u32
    uint32_t* ws_pkey = ws_bkey + (size_t)NB * NSB * KSLOT;    // 64*9*192 u32
    // total ws: 2,113,536 B (within proven budget)

    // LDS: tile 19200 + surv 3072 + hist 1024 + outb 768 = 24064 B -> 4 blk/CU
    size_t lds1 = (size_t)(SR + 2) * WB * 4 + (size_t)CAP * 4 + 1024 + (size_t)KSLOT * 4;
    stage1<<<dim3(NSB + NSP, NB), TPB, lds1, stream>>>(bmap, pmap, ws_bkey, ws_pkey);

    // LDS: keys 26112 + hist 1024 + outb 2048 = 29184 B
    size_t lds2 = (size_t)NSB * KSLOT * 4 + 1024 + 2048;
    stage2<<<2 * NB, TPB, lds2, stream>>>(bmap, pmap, pbbox, ws_bkey, ws_pkey, out);
}

// Round 3
// 139.376 us; speedup vs baseline: 1.0552x; 1.0552x over previous
//
#include <hip/hip_runtime.h>
#include <stdint.h>
#include <math.h>

#define TPB   512    // 8 waves/block -> 4 blocks/CU hits the 32-wave cap
#define KTOP  100
#define K1    128    // selection rank cut (per-slice in s1, per-image in s2)
#define KSLOT 192    // per-slice emitted u32 slots (>= K1 + tie-bin margin)
#define CAP   768    // stage-1 survivor capacity (expected ~450/slice, +13 sigma)
#define SR    8      // slice rows

#define HB 272
#define WB 480
#define NSB 34       // 272/8
#define HP 68
#define WP 120
#define NSP 9        // ceil(68/8), last slice 4 rows
#define NB 64

// ============================================================================
// Validated invariants (rounds 2-5 of prior session, absmax 0.0):
//  - np-f32 softmax p is a MONOTONE function G of D = fl32(x1-x0);
//    G collapse window |dD| < ~6e-8*e^|D| (< 0.25 for |D| < 13).
//  - NMS: keep iff p >= all 8 neighbors; D-space fast path + exact G on ties.
//  - top-k tie order: (p desc, idx asc)  ==  u64 key (p_bits<<32 | ~idx) desc.
//  - 16-bit D-key rank-128 cut contains the exact top-100 set.
// R8 (recombination):
//  - stage1 = R0 form exactly (plain atomics, inline tie G; R6 queue cost
//    +3.6us, R7 ballots cost +8us: per-cell ballot chains >> 12%-density
//    atomics; stage1 is stall-bound, not VALU/atomic-bound).
//  - stage2 = R7 form (clustered lvl-1 hist + rank-by-counting: -7us vs
//    bitonic, measured).
//  - both: scratch (outb/hist2/rnk) pre-zeroed before the first barrier ->
//    2 fewer barrier-separated phases per block.
// ============================================================================
__device__ __forceinline__ float G_exact(float D) {
    float t = -fabsf(D);
    float etf = (float)exp((double)t);       // correctly-rounded f32 exp
    return (D > 0.0f) ? __fdiv_rn(1.0f, __fadd_rn(etf, 1.0f))
                      : __fdiv_rn(etf, __fadd_rn(1.0f, etf));
}

__device__ __forceinline__ uint32_t flip_f32(float D) {
    uint32_t u = __float_as_uint(D);
    return (u & 0x80000000u) ? ~u : (u | 0x80000000u);
}

// Wave-aggregated counter push (stage2 only: low-frequency call sites).
__device__ __forceinline__ int agg_push(int* ctr, bool active) {
    uint64_t m = __ballot(active);
    int pos = -1;
    if (active) {
        int lane = threadIdx.x & 63;
        int lead = __ffsll((unsigned long long)m) - 1;
        int before = (int)__popcll(m & ((1ull << lane) - 1ull));
        int base = 0;
        if (lane == lead) base = atomicAdd(ctr, (int)__popcll(m));
        base = __shfl(base, lead, 64);
        pos = base + before;
    }
    return pos;
}

// Clustered histogram add (stage2 load pass only): one atomicAdd per
// DISTINCT bin per wave.
__device__ __forceinline__ void hist_clustered(uint32_t* hist, uint32_t bin, bool active) {
    uint64_t todo = __ballot(active);
    while (todo) {
        int lead = __ffsll((unsigned long long)todo) - 1;
        uint32_t b = (uint32_t)__shfl((int)bin, lead, 64);
        uint64_t same = __ballot(active && (bin == b));
        if ((int)(threadIdx.x & 63) == lead) atomicAdd(&hist[b], (uint32_t)__popcll(same));
        todo &= ~same;
    }
}

// In-place suffix-sum of 256 u32 bins: hist[i] <- sum_{j>=i} hist[j].
// Wave 0 via shuffles; ends with a barrier. (validated round 4)
__device__ __forceinline__ void suffix_scan_256(uint32_t* hist) {
    if (threadIdx.x < 64) {
        int lane = threadIdx.x;
        uint32_t h0 = hist[4*lane+0], h1 = hist[4*lane+1];
        uint32_t h2 = hist[4*lane+2], h3 = hist[4*lane+3];
        uint32_t tot = h0 + h1 + h2 + h3;
        uint32_t run = tot;
        #pragma unroll
        for (int d = 1; d < 64; d <<= 1) {
            uint32_t o = __shfl_down(run, d, 64);
            if (lane + d < 64) run += o;
        }
        uint32_t ab = run - tot;
        hist[4*lane+3] = ab + h3;
        hist[4*lane+2] = ab + h3 + h2;
        hist[4*lane+1] = ab + h3 + h2 + h1;
        hist[4*lane+0] = ab + tot;
    }
    __syncthreads();
}

// 6-wide row window [c4-1 .. c4+4] from the LDS D-tile (OOB -> -inf).
template<int W>
__device__ __forceinline__ void row6(const float* df, int row, int c4, float* a) {
    const float4 m = ((const float4*)df)[(row * W + c4) >> 2];
    a[1] = m.x; a[2] = m.y; a[3] = m.z; a[4] = m.w;
    a[0] = (c4 > 0)     ? df[row * W + c4 - 1] : -INFINITY;
    a[5] = (c4 + 4 < W) ? df[row * W + c4 + 4] : -INFINITY;
}

// ---- stage 1 body: NMS + D16 radix-select, emit u32 slots ------------------
// Templated W/H/NS -> all divisions become compile-time magic-mul/shift.
template<int H, int W, int NS>
__device__ __forceinline__ void stage1_impl(const float* __restrict__ x,
                                            int s, int b,
                                            uint32_t* __restrict__ key_out,
                                            unsigned char* smem)
{
    constexpr int W4 = W / 4;
    constexpr int tileRows = SR + 2;
    const int r0 = s * SR;
    const int rows = (H - r0 < SR) ? (H - r0) : SR;

    float*    df    = (float*)smem;                        // tileRows * W
    uint32_t* surv  = (uint32_t*)(df + tileRows * W);      // CAP
    uint32_t* hist  = surv + CAP;                          // 256
    uint32_t* hist2 = hist + 256;                          // 256 (level-2)
    uint32_t* outb  = hist2 + 256;                         // KSLOT
    __shared__ int s_cnt, s_out;
    __shared__ uint32_t s_bin, s_ab, s_bin2, s_none;
    if (threadIdx.x == 0) { s_cnt = 0; s_out = 0; s_none = 0; }
    if (threadIdx.x < 256) { hist[threadIdx.x] = 0; hist2[threadIdx.x] = 0; }
    if (threadIdx.x < KSLOT) outb[threadIdx.x] = 0;

    const float*  x0  = x + (size_t)b * 2 * H * W;
    const float*  x1  = x0 + (size_t)H * W;
    const float4* x0v = (const float4*)x0;
    const float4* x1v = (const float4*)x1;
    float4* dfv = (float4*)df;

    // D tile (rows r0-1 .. r0+SR), float4-vectorized; OOB rows -> -inf.
    constexpr int nt4 = tileRows * W4;
    for (int t = threadIdx.x; t < nt4; t += TPB) {
        int tr = t / W4, c4 = t - tr * W4;        // compile-time divisor
        int r = r0 - 1 + tr;
        float4 d4 = make_float4(-INFINITY, -INFINITY, -INFINITY, -INFINITY);
        if (r >= 0 && r < H) {
            float4 a = x0v[r * W4 + c4];
            float4 c = x1v[r * W4 + c4];
            d4.x = __fsub_rn(c.x, a.x);
            d4.y = __fsub_rn(c.y, a.y);
            d4.z = __fsub_rn(c.z, a.z);
            d4.w = __fsub_rn(c.w, a.w);
        }
        dfv[t] = d4;
    }
    __syncthreads();

    // NMS (4 cells/iter) + level-1 histogram fused into the keep path.
    const int groups = rows * W4;
    for (int g = threadIdx.x; g < groups; g += TPB) {
        int lr = g / W4, c4 = (g - lr * W4) << 2; // compile-time divisor
        int tr = lr + 1;
        float ap[6], ac[6], an[6];
        row6<W>(df, tr - 1, c4, ap);
        row6<W>(df, tr,     c4, ac);
        row6<W>(df, tr + 1, c4, an);
        #pragma unroll
        for (int j = 0; j < 4; ++j) {
            float v = ac[j + 1];
            float mx = fmaxf(fmaxf(fmaxf(ap[j], ap[j+1]), fmaxf(ap[j+2], an[j])),
                             fmaxf(fmaxf(an[j+1], an[j+2]), fmaxf(ac[j], ac[j+2])));
            bool keep;
            if (v >= mx) keep = true;                              // exact
            else if (mx - v >= 0.25f && mx < 13.0f) keep = false;  // G distinct
            else keep = (G_exact(v) == G_exact(mx));               // rare tie
            if (keep) {
                uint32_t key16 = flip_f32(v) >> 16;
                int pos = atomicAdd(&s_cnt, 1);
                if (pos < CAP)
                    surv[pos] = (key16 << 16) | ((uint32_t)lr << 9) | (uint32_t)(c4 + j);
                atomicAdd(&hist[key16 >> 8], 1u);
            }
        }
    }
    __syncthreads();
    const int n = (s_cnt < CAP) ? s_cnt : CAP;

    // Level-1 select on D16 high byte.
    suffix_scan_256(hist);
    if (threadIdx.x < 256) {
        uint32_t si = hist[threadIdx.x];
        uint32_t sn = (threadIdx.x < 255) ? hist[threadIdx.x + 1] : 0u;
        if (threadIdx.x == 0 && si < K1) s_none = 1;
        if (si >= K1 && sn < K1) { s_bin = threadIdx.x; s_ab = sn; }
    }
    __syncthreads();

    uint32_t T16 = 0;
    if (!s_none) {
        const uint32_t b3 = s_bin;
        const uint32_t k2 = K1 - s_ab;
        // Level-2: hist2 pre-zeroed in the init phase (no rezero barrier).
        for (int t = threadIdx.x; t < n; t += TPB) {
            uint32_t sv = surv[t];
            if ((sv >> 24) == b3) atomicAdd(&hist2[(sv >> 16) & 255u], 1u);
        }
        __syncthreads();
        suffix_scan_256(hist2);
        if (threadIdx.x < 256) {
            uint32_t si = hist2[threadIdx.x];
            uint32_t sn = (threadIdx.x < 255) ? hist2[threadIdx.x + 1] : 0u;
            if (si >= k2 && sn < k2) s_bin2 = threadIdx.x;
        }
        __syncthreads();
        T16 = (b3 << 8) | s_bin2;
    }

    // Compact survivors with D16 >= T16 (unsorted) into pre-zeroed outb.
    for (int t = threadIdx.x; t < n; t += TPB) {
        uint32_t sv = surv[t];
        if ((sv >> 16) >= T16) {
            int pos = atomicAdd(&s_out, 1);
            if (pos < KSLOT) outb[pos] = sv;
        }
    }
    __syncthreads();
    if (threadIdx.x < KSLOT)
        key_out[((size_t)b * NS + s) * KSLOT + threadIdx.x] = outb[threadIdx.x];
}

__global__ __launch_bounds__(TPB) void stage1(const float* __restrict__ bmap,
                                              const float* __restrict__ pmap,
                                              uint32_t* __restrict__ bkey,
                                              uint32_t* __restrict__ pkey)
{
    extern __shared__ unsigned char smem[];
    if (blockIdx.x < NSB)
        stage1_impl<HB, WB, NSB>(bmap, blockIdx.x, blockIdx.y, bkey, smem);
    else
        stage1_impl<HP, WP, NSP>(pmap, blockIdx.x - NSB, blockIdx.y, pkey, smem);
}

// ---- stage 2 body: D16 select -> exact-p re-rank of <=256 -> decode --------
template<int H, int W, int NS, bool BALL>
__device__ __forceinline__ void stage2_impl(const float* __restrict__ xmap,
                                            const float* __restrict__ pbbox,
                                            const uint32_t* __restrict__ key_in,
                                            float* __restrict__ outp,
                                            int b, unsigned char* smem)
{
    constexpr int M = NS * KSLOT;
    const float* x0 = xmap + (size_t)b * 2 * H * W;
    const float* x1 = x0 + (size_t)H * W;
    const uint32_t* kin = key_in + (size_t)b * M;

    uint32_t* keys  = (uint32_t*)smem;           // M
    uint32_t* hist  = keys + M;                  // 256 (level-1)
    uint32_t* hist2 = hist + 256;                // 256 (level-2)
    uint32_t* rnk   = hist2 + 256;               // 256 (ranks)
    uint64_t* outb  = (uint64_t*)(rnk + 256);    // 256
    __shared__ int s_out;
    __shared__ uint32_t s_bin, s_ab, s_bin2, s_none;
    if (threadIdx.x == 0) { s_out = 0; s_none = 0; }
    if (threadIdx.x < 256) {
        hist[threadIdx.x] = 0; hist2[threadIdx.x] = 0;
        rnk[threadIdx.x] = 0; outb[threadIdx.x] = 0;
    }
    // Defensive zero of the 100 output rows (rank-scatter fills real rows).
    for (int t = threadIdx.x; t < KTOP * 5; t += TPB) outp[t] = 0.f;
    __syncthreads();

    // Load keys + level-1 histogram in one pass (clustered bin atomics:
    // hot-bin lane serialization would cost ~5100 serialized adds here).
    for (int t = threadIdx.x; t < M; t += TPB) {
        uint32_t k = kin[t];
        keys[t] = k;
        hist_clustered(hist, k >> 24, k != 0);
    }
    __syncthreads();
    suffix_scan_256(hist);
    if (threadIdx.x < 256) {
        uint32_t si = hist[threadIdx.x];
        uint32_t sn = (threadIdx.x < 255) ? hist[threadIdx.x + 1] : 0u;
        if (threadIdx.x == 0 && si < K1) s_none = 1;
        if (si >= K1 && sn < K1) { s_bin = threadIdx.x; s_ab = sn; }
    }
    __syncthreads();

    uint32_t T16 = 0;
    if (!s_none) {
        const uint32_t b3 = s_bin;
        const uint32_t k2 = K1 - s_ab;
        // Level-2: hist2 pre-zeroed in the init phase.
        for (int t = threadIdx.x; t < M; t += TPB) {
            uint32_t k = keys[t];
            if (k && (k >> 24) == b3) atomicAdd(&hist2[(k >> 16) & 255u], 1u);
        }
        __syncthreads();
        suffix_scan_256(hist2);
        if (threadIdx.x < 256) {
            uint32_t si = hist2[threadIdx.x];
            uint32_t sn = (threadIdx.x < 255) ? hist2[threadIdx.x + 1] : 0u;
            if (si >= k2 && sn < k2) s_bin2 = threadIdx.x;
        }
        __syncthreads();
        T16 = (b3 << 8) | s_bin2;
    }

    // Compact finalists into pre-zeroed outb; exact np p computed only here.
    for (int t = threadIdx.x; t < M; t += TPB) {
        uint32_t k = keys[t];
        bool take = (k != 0) && ((k >> 16) >= T16);
        int pos = agg_push(&s_out, take);
        if (take && pos < 256) {
            int sIdx = t / KSLOT;                      // compile-time divisor
            int lr = (k >> 9) & 7, c = k & 511;
            int gidx = (sIdx * SR + lr) * W + c;
            float D = __fsub_rn(x1[gidx], x0[gidx]);
            float p = G_exact(D);
            outb[pos] = ((uint64_t)__float_as_uint(p) << 32) | (uint32_t)(~gidx);
        }
    }
    __syncthreads();

    // Rank-by-counting over unique u64 keys (2 barriers vs bitonic's 36).
    // Thread (i = tid&255, half = tid>>8) counts keys greater than outb[i]
    // over half the array; j is wave-uniform -> LDS broadcast reads.
    {
        int i = threadIdx.x & 255;
        int half = threadIdx.x >> 8;
        uint64_t ki = outb[i];
        uint32_t cnt = 0;
        int j0 = half * 128;
        #pragma unroll 4
        for (int j = j0; j < j0 + 128; ++j) cnt += (outb[j] > ki) ? 1u : 0u;
        atomicAdd(&rnk[i], cnt);
    }
    __syncthreads();

    // Decode: finalist with rank r < KTOP writes output row r directly.
    if (threadIdx.x < 256) {
        uint64_t k = outb[threadIdx.x];
        uint32_t r = rnk[threadIdx.x];
        if (k != 0 && r < KTOP) {
            int id = (int)(~(uint32_t)k);
            float val = __uint_as_float((uint32_t)(k >> 32));
            int yy = id / W, xx = id - yy * W;             // compile-time divisor
            constexpr float ds = BALL ? 4.0f : 16.0f;
            float xc = (float)xx * ds + (ds - 1.0f) * 0.5f;
            float yc = (float)yy * ds + (ds - 1.0f) * 0.5f;
            float t0 = 0.f, t1 = 0.f;
            float t2 = BALL ? 40.0f : 0.0f, t3 = BALL ? 40.0f : 0.0f;
            if (!BALL) {
                const float* bb = pbbox + (size_t)b * 4 * H * W;
                constexpr float sx = (float)W * ds, sy = (float)H * ds;
                t0 = bb[id]             * sx;
                t1 = bb[id + H * W]     * sy;
                t2 = bb[id + 2 * H * W] * sx;
                t3 = bb[id + 3 * H * W] * sy;
            }
            float bx = xc + t0, by = yc + t1;
            float* op = outp + (size_t)r * 5;
            op[0] = bx - 0.5f * t2;
            op[1] = by - 0.5f * t3;
            op[2] = bx + 0.5f * t2;
            op[3] = by + 0.5f * t3;
            op[4] = val;
        }
    }
}

__global__ __launch_bounds__(TPB) void stage2(const float* __restrict__ bmap,
                                              const float* __restrict__ pmap,
                                              const float* __restrict__ pbbox,
                                              const uint32_t* __restrict__ bkey,
                                              const uint32_t* __restrict__ pkey,
                                              float* __restrict__ out)
{
    extern __shared__ unsigned char smem[];
    if (blockIdx.x < NB) {
        int b = blockIdx.x;
        stage2_impl<HB, WB, NSB, true>(bmap, nullptr, bkey,
            out + (size_t)NB * KTOP * 5 + (size_t)b * KTOP * 5, b, smem);
    } else {
        int b = blockIdx.x - NB;
        stage2_impl<HP, WP, NSP, false>(pmap, pbbox, pkey,
            out + (size_t)b * KTOP * 5, b, smem);
    }
}

// ---- launch -----------------------------------------------------------------
extern "C" void kernel_launch(void* const* d_in, const int* in_sizes, int n_in,
                              void* d_out, int out_size, void* d_ws, size_t ws_size,
                              hipStream_t stream) {
    const float* pmap  = (const float*)d_in[0];   // [64,2,68,120]
    const float* pbbox = (const float*)d_in[1];   // [64,4,68,120]
    const float* bmap  = (const float*)d_in[2];   // [64,2,272,480]
    float* out = (float*)d_out;                   // player [64,100,5] then ball

    uint32_t* ws_bkey = (uint32_t*)d_ws;                       // 64*34*192 u32
    uint32_t* ws_pkey = ws_bkey + (size_t)NB * NSB * KSLOT;    // 64*9*192 u32
    // total ws: 2,113,536 B (within proven budget)

    // LDS: tile 19200 + surv 3072 + hist 1024 + hist2 1024 + outb 768
    //    = 25088 B -> 4 blk/CU (wave-capped)
    size_t lds1 = (size_t)(SR + 2) * WB * 4 + (size_t)CAP * 4 + 2048 + (size_t)KSLOT * 4;
    stage1<<<dim3(NSB + NSP, NB), TPB, lds1, stream>>>(bmap, pmap, ws_bkey, ws_pkey);

    // LDS: keys 26112 + hist 1024 + hist2 1024 + rnk 1024 + outb 2048 = 31232 B
    size_t lds2 = (size_t)NSB * KSLOT * 4 + 3072 + 2048;
    stage2<<<2 * NB, TPB, lds2, stream>>>(bmap, pmap, pbbox, ws_bkey, ws_pkey, out);
}